// Round 2
// baseline (789.940 us; speedup 1.0000x reference)
//
#include <hip/hip_runtime.h>
#include <math.h>

#define N_NODES 100000
#define F_IN    512
#define E_EDGES 3200000

// ---- K1: init workspace (deg=1.0 for self-loop weight, accum=0, logit=0) ----
__global__ void k_init(float* __restrict__ deg, float* __restrict__ accum,
                       float* __restrict__ logit) {
    int i = blockIdx.x * blockDim.x + threadIdx.x;
    if (i < N_NODES) {
        deg[i] = 1.0f;          // self-loop fill weight
        accum[2 * i]     = 0.0f;
        accum[2 * i + 1] = 0.0f;
    }
    if (i == 0) logit[0] = 0.0f;
}

// ---- K2: degree scatter: deg[col[e]] += edge_attr[e] ----
__global__ void k_deg(const int* __restrict__ col,
                      const float* __restrict__ w,
                      float* __restrict__ deg) {
    int e = blockIdx.x * blockDim.x + threadIdx.x;
    if (e < E_EDGES) {
        atomicAdd(&deg[col[e]], w[e]);
    }
}

// ---- K3: deg -> deg^{-1/2} in place (deg >= 1 guaranteed by self-loop) ----
__global__ void k_rsqrt(float* __restrict__ deg) {
    int i = blockIdx.x * blockDim.x + threadIdx.x;
    if (i < N_NODES) deg[i] = rsqrtf(deg[i]);
}

// ---- K4: h = x @ W  (wave-per-row, float4 coalesced, memory-bound) ----
__global__ __launch_bounds__(256) void k_gemv(const float* __restrict__ x,
                                              const float* __restrict__ W,
                                              float* __restrict__ h) {
    int row  = (blockIdx.x * blockDim.x + threadIdx.x) >> 6;  // wave id
    int lane = threadIdx.x & 63;
    if (row >= N_NODES) return;
    const float* xr = x + (size_t)row * F_IN;
    float a0 = 0.0f, a1 = 0.0f;
#pragma unroll
    for (int c = 0; c < 2; ++c) {
        int k = c * 256 + lane * 4;                    // contiguous 1KB per wave-load
        float4 xv  = *(const float4*)(xr + k);
        float4 w01 = *(const float4*)(W + 2 * k);      // W[k][0..1], W[k+1][0..1]
        float4 w23 = *(const float4*)(W + 2 * k + 4);  // W[k+2][0..1], W[k+3][0..1]
        a0 += xv.x * w01.x + xv.y * w01.z + xv.z * w23.x + xv.w * w23.z;
        a1 += xv.x * w01.y + xv.y * w01.w + xv.z * w23.y + xv.w * w23.w;
    }
#pragma unroll
    for (int off = 32; off > 0; off >>= 1) {
        a0 += __shfl_down(a0, off, 64);
        a1 += __shfl_down(a1, off, 64);
    }
    if (lane == 0) { h[2 * row] = a0; h[2 * row + 1] = a1; }
}

// ---- K5: message scatter: accum[col] += h[row] * dis[row]*w*dis[col] ----
__global__ void k_prop(const int* __restrict__ row,
                       const int* __restrict__ col,
                       const float* __restrict__ w,
                       const float* __restrict__ dis,
                       const float* __restrict__ h,
                       float* __restrict__ accum) {
    int e = blockIdx.x * blockDim.x + threadIdx.x;
    if (e < E_EDGES) {
        int r = row[e];
        int c = col[e];
        float nm = dis[r] * w[e] * dis[c];
        float h0 = h[2 * r];
        float h1 = h[2 * r + 1];
        atomicAdd(&accum[2 * c],     h0 * nm);
        atomicAdd(&accum[2 * c + 1], h1 * nm);
    }
}

// ---- K6: self-loop + bias + relu + fc dot, block-reduced into logit ----
__global__ __launch_bounds__(256) void k_epilogue(const float* __restrict__ accum,
                                                  const float* __restrict__ h,
                                                  const float* __restrict__ dis,
                                                  const float* __restrict__ b,
                                                  const float* __restrict__ fc_w,
                                                  float* __restrict__ logit) {
    int i = blockIdx.x * blockDim.x + threadIdx.x;
    float partial = 0.0f;
    if (i < N_NODES) {
        float d2 = dis[i] * dis[i];                 // self-loop norm (w=1)
        float o0 = accum[2 * i]     + h[2 * i]     * d2 + b[0];
        float o1 = accum[2 * i + 1] + h[2 * i + 1] * d2 + b[1];
        o0 = fmaxf(o0, 0.0f);
        o1 = fmaxf(o1, 0.0f);
        partial = o0 * fc_w[2 * i] + o1 * fc_w[2 * i + 1];
    }
#pragma unroll
    for (int off = 32; off > 0; off >>= 1)
        partial += __shfl_down(partial, off, 64);
    __shared__ float sdata[4];
    int lane = threadIdx.x & 63, wid = threadIdx.x >> 6;
    if (lane == 0) sdata[wid] = partial;
    __syncthreads();
    if (threadIdx.x == 0)
        atomicAdd(logit, sdata[0] + sdata[1] + sdata[2] + sdata[3]);
}

// ---- K7: sigmoid ----
__global__ void k_sigmoid(const float* __restrict__ logit,
                          const float* __restrict__ fc_b,
                          float* __restrict__ out) {
    float z = logit[0] + fc_b[0];
    out[0] = 1.0f / (1.0f + expf(-z));
}

extern "C" void kernel_launch(void* const* d_in, const int* in_sizes, int n_in,
                              void* d_out, int out_size, void* d_ws, size_t ws_size,
                              hipStream_t stream) {
    const float* x   = (const float*)d_in[0];
    const int*   el  = (const int*)d_in[1];    // [2, E] — harness stores ints as int32
    const float* ea  = (const float*)d_in[2];
    const float* W   = (const float*)d_in[3];
    const float* b   = (const float*)d_in[4];
    const float* fcw = (const float*)d_in[5];
    const float* fcb = (const float*)d_in[6];
    float*       out = (float*)d_out;

    float* ws    = (float*)d_ws;
    float* deg   = ws;                    // N   (becomes deg^{-1/2} in place)
    float* h     = ws + N_NODES;          // 2N
    float* accum = ws + 3 * N_NODES;      // 2N
    float* logit = ws + 5 * N_NODES;      // 1

    const int* row = el;
    const int* col = el + E_EDGES;

    const int TB = 256;
    dim3 gN((N_NODES + TB - 1) / TB);
    dim3 gE((E_EDGES + TB - 1) / TB);
    dim3 gG((N_NODES * 64 + TB - 1) / TB);   // wave-per-row

    k_init    <<<gN, TB, 0, stream>>>(deg, accum, logit);
    k_deg     <<<gE, TB, 0, stream>>>(col, ea, deg);
    k_rsqrt   <<<gN, TB, 0, stream>>>(deg);
    k_gemv    <<<gG, TB, 0, stream>>>(x, W, h);
    k_prop    <<<gE, TB, 0, stream>>>(row, col, ea, deg, h, accum);
    k_epilogue<<<gN, TB, 0, stream>>>(accum, h, deg, b, fcw, logit);
    k_sigmoid <<<1, 1, 0, stream>>>(logit, fcb, out);
}

// Round 3
// 467.039 us; speedup vs baseline: 1.6914x; 1.6914x over previous
//
#include <hip/hip_runtime.h>
#include <math.h>

#define N_NODES 100000
#define F_IN    512
#define E_EDGES 3200000

// --- tiled-scatter geometry ---
#define NR   16                 // node ranges
#define RN   6250               // nodes per range (NR*RN == N_NODES)
#define REP  16                 // edge-chunk replicas
#define CHUNK (E_EDGES / REP)   // 200000, multiple of 4

// ====================== fast path (LDS-tiled scatter) ======================

// deg scatter: block (r,p) accumulates attr of cols in range r from chunk p.
__global__ __launch_bounds__(1024) void k_deg_tiled(const int* __restrict__ col,
                                                    const float* __restrict__ w,
                                                    float* __restrict__ rep_deg) {
    __shared__ float sdeg[RN];
    int r = blockIdx.x / REP, p = blockIdx.x % REP;
    int r0 = r * RN;
    for (int j = threadIdx.x; j < RN; j += 1024) sdeg[j] = 0.0f;
    __syncthreads();
    const int*   colc = col + p * CHUNK;
    const float* wc   = w   + p * CHUNK;
    for (int e4 = threadIdx.x * 4; e4 < CHUNK; e4 += 4096) {
        int4   c4 = *(const int4*)(colc + e4);
        float4 w4 = *(const float4*)(wc + e4);
        unsigned j;
        j = (unsigned)(c4.x - r0); if (j < RN) atomicAdd(&sdeg[j], w4.x);
        j = (unsigned)(c4.y - r0); if (j < RN) atomicAdd(&sdeg[j], w4.y);
        j = (unsigned)(c4.z - r0); if (j < RN) atomicAdd(&sdeg[j], w4.z);
        j = (unsigned)(c4.w - r0); if (j < RN) atomicAdd(&sdeg[j], w4.w);
    }
    __syncthreads();
    float* out = rep_deg + (size_t)blockIdx.x * RN;
    for (int j = threadIdx.x; j < RN; j += 1024) out[j] = sdeg[j];
}

// reduce replicas, add self-loop weight 1, rsqrt -> dis; zero logit
__global__ void k_dis(const float* __restrict__ rep_deg,
                      float* __restrict__ dis, float* __restrict__ logit) {
    int i = blockIdx.x * blockDim.x + threadIdx.x;
    if (i < N_NODES) {
        int r = i / RN, j = i - r * RN;
        const float* base = rep_deg + (size_t)(r * REP) * RN + j;
        float d = 1.0f;
#pragma unroll
        for (int p = 0; p < REP; ++p) d += base[p * RN];
        dis[i] = rsqrtf(d);
    }
    if (i == 0) logit[0] = 0.0f;
}

// message scatter: accum[col] += h[row] * dis[row]*w*dis[col], LDS-tiled
__global__ __launch_bounds__(1024) void k_prop_tiled(const int* __restrict__ row,
                                                     const int* __restrict__ col,
                                                     const float* __restrict__ w,
                                                     const float* __restrict__ dis,
                                                     const float* __restrict__ h,
                                                     float* __restrict__ rep_acc) {
    __shared__ float sacc[RN * 2];
    int r = blockIdx.x / REP, p = blockIdx.x % REP;
    int r0 = r * RN;
    for (int j = threadIdx.x; j < RN * 2; j += 1024) sacc[j] = 0.0f;
    __syncthreads();
    const int*   colc = col + p * CHUNK;
    const int*   rowc = row + p * CHUNK;
    const float* wc   = w   + p * CHUNK;
    for (int e4 = threadIdx.x * 4; e4 < CHUNK; e4 += 4096) {
        int4 c4 = *(const int4*)(colc + e4);
#pragma unroll
        for (int q = 0; q < 4; ++q) {
            int c = (&c4.x)[q];
            unsigned j = (unsigned)(c - r0);
            if (j < RN) {
                int e  = e4 + q;
                int rr = rowc[e];
                float nm = dis[rr] * wc[e] * dis[c];
                float2 hv = *(const float2*)(h + 2 * rr);
                atomicAdd(&sacc[2 * j],     hv.x * nm);
                atomicAdd(&sacc[2 * j + 1], hv.y * nm);
            }
        }
    }
    __syncthreads();
    float* out = rep_acc + (size_t)blockIdx.x * (RN * 2);
    for (int j = threadIdx.x; j < RN * 2; j += 1024) out[j] = sacc[j];
}

// reduce replicas + self-loop + bias + relu + fc dot -> logit
__global__ __launch_bounds__(256) void k_epilogue_tiled(const float* __restrict__ rep_acc,
                                                        const float* __restrict__ h,
                                                        const float* __restrict__ dis,
                                                        const float* __restrict__ b,
                                                        const float* __restrict__ fc_w,
                                                        float* __restrict__ logit) {
    int i = blockIdx.x * blockDim.x + threadIdx.x;
    float partial = 0.0f;
    if (i < N_NODES) {
        int r = i / RN, j = i - r * RN;
        const float2* base = (const float2*)rep_acc + (size_t)(r * REP) * RN + j;
        float o0 = 0.0f, o1 = 0.0f;
#pragma unroll
        for (int p = 0; p < REP; ++p) { float2 v = base[p * RN]; o0 += v.x; o1 += v.y; }
        float d2 = dis[i] * dis[i];
        o0 += h[2 * i]     * d2 + b[0];
        o1 += h[2 * i + 1] * d2 + b[1];
        o0 = fmaxf(o0, 0.0f); o1 = fmaxf(o1, 0.0f);
        partial = o0 * fc_w[2 * i] + o1 * fc_w[2 * i + 1];
    }
#pragma unroll
    for (int off = 32; off > 0; off >>= 1)
        partial += __shfl_down(partial, off, 64);
    __shared__ float sdata[4];
    int lane = threadIdx.x & 63, wid = threadIdx.x >> 6;
    if (lane == 0) sdata[wid] = partial;
    __syncthreads();
    if (threadIdx.x == 0)
        atomicAdd(logit, sdata[0] + sdata[1] + sdata[2] + sdata[3]);
}

// ====================== shared kernels ======================

// h = x @ W  (wave-per-row, float4 coalesced, memory-bound)
__global__ __launch_bounds__(256) void k_gemv(const float* __restrict__ x,
                                              const float* __restrict__ W,
                                              float* __restrict__ h) {
    int row  = (blockIdx.x * blockDim.x + threadIdx.x) >> 6;
    int lane = threadIdx.x & 63;
    if (row >= N_NODES) return;
    const float* xr = x + (size_t)row * F_IN;
    float a0 = 0.0f, a1 = 0.0f;
#pragma unroll
    for (int c = 0; c < 2; ++c) {
        int k = c * 256 + lane * 4;
        float4 xv  = *(const float4*)(xr + k);
        float4 w01 = *(const float4*)(W + 2 * k);
        float4 w23 = *(const float4*)(W + 2 * k + 4);
        a0 += xv.x * w01.x + xv.y * w01.z + xv.z * w23.x + xv.w * w23.z;
        a1 += xv.x * w01.y + xv.y * w01.w + xv.z * w23.y + xv.w * w23.w;
    }
#pragma unroll
    for (int off = 32; off > 0; off >>= 1) {
        a0 += __shfl_down(a0, off, 64);
        a1 += __shfl_down(a1, off, 64);
    }
    if (lane == 0) { h[2 * row] = a0; h[2 * row + 1] = a1; }
}

__global__ void k_sigmoid(const float* __restrict__ logit,
                          const float* __restrict__ fc_b,
                          float* __restrict__ out) {
    float z = logit[0] + fc_b[0];
    out[0] = 1.0f / (1.0f + expf(-z));
}

// ====================== fallback path (device atomics) ======================

__global__ void k_init(float* __restrict__ deg, float* __restrict__ accum,
                       float* __restrict__ logit) {
    int i = blockIdx.x * blockDim.x + threadIdx.x;
    if (i < N_NODES) {
        deg[i] = 1.0f;
        accum[2 * i] = 0.0f;
        accum[2 * i + 1] = 0.0f;
    }
    if (i == 0) logit[0] = 0.0f;
}

__global__ void k_deg(const int* __restrict__ col, const float* __restrict__ w,
                      float* __restrict__ deg) {
    int e = blockIdx.x * blockDim.x + threadIdx.x;
    if (e < E_EDGES) atomicAdd(&deg[col[e]], w[e]);
}

__global__ void k_rsqrt(float* __restrict__ deg) {
    int i = blockIdx.x * blockDim.x + threadIdx.x;
    if (i < N_NODES) deg[i] = rsqrtf(deg[i]);
}

__global__ void k_prop(const int* __restrict__ row, const int* __restrict__ col,
                       const float* __restrict__ w, const float* __restrict__ dis,
                       const float* __restrict__ h, float* __restrict__ accum) {
    int e = blockIdx.x * blockDim.x + threadIdx.x;
    if (e < E_EDGES) {
        int r = row[e], c = col[e];
        float nm = dis[r] * w[e] * dis[c];
        atomicAdd(&accum[2 * c],     h[2 * r] * nm);
        atomicAdd(&accum[2 * c + 1], h[2 * r + 1] * nm);
    }
}

__global__ __launch_bounds__(256) void k_epilogue(const float* __restrict__ accum,
                                                  const float* __restrict__ h,
                                                  const float* __restrict__ dis,
                                                  const float* __restrict__ b,
                                                  const float* __restrict__ fc_w,
                                                  float* __restrict__ logit) {
    int i = blockIdx.x * blockDim.x + threadIdx.x;
    float partial = 0.0f;
    if (i < N_NODES) {
        float d2 = dis[i] * dis[i];
        float o0 = accum[2 * i]     + h[2 * i]     * d2 + b[0];
        float o1 = accum[2 * i + 1] + h[2 * i + 1] * d2 + b[1];
        o0 = fmaxf(o0, 0.0f); o1 = fmaxf(o1, 0.0f);
        partial = o0 * fc_w[2 * i] + o1 * fc_w[2 * i + 1];
    }
#pragma unroll
    for (int off = 32; off > 0; off >>= 1)
        partial += __shfl_down(partial, off, 64);
    __shared__ float sdata[4];
    int lane = threadIdx.x & 63, wid = threadIdx.x >> 6;
    if (lane == 0) sdata[wid] = partial;
    __syncthreads();
    if (threadIdx.x == 0)
        atomicAdd(logit, sdata[0] + sdata[1] + sdata[2] + sdata[3]);
}

// ====================== launch ======================

extern "C" void kernel_launch(void* const* d_in, const int* in_sizes, int n_in,
                              void* d_out, int out_size, void* d_ws, size_t ws_size,
                              hipStream_t stream) {
    const float* x   = (const float*)d_in[0];
    const int*   el  = (const int*)d_in[1];    // [2, E] int32 on device
    const float* ea  = (const float*)d_in[2];
    const float* W   = (const float*)d_in[3];
    const float* b   = (const float*)d_in[4];
    const float* fcw = (const float*)d_in[5];
    const float* fcb = (const float*)d_in[6];
    float*       out = (float*)d_out;

    const int* row = el;
    const int* col = el + E_EDGES;

    float* ws = (float*)d_ws;
    const int TB = 256;
    dim3 gN((N_NODES + TB - 1) / TB);
    dim3 gG((N_NODES * 64 + TB - 1) / TB);

    // fast-path ws layout (floats):
    // h[2N] | dis[N] | rep_deg[NR*REP*RN] | rep_acc[NR*REP*RN*2] | logit[1]
    const size_t need_fast = (size_t)(2 * N_NODES + N_NODES +
                                      NR * REP * RN + NR * REP * RN * 2 + 64) * 4;

    if (ws_size >= need_fast) {
        float* h       = ws;
        float* dis     = ws + 2 * N_NODES;
        float* rep_deg = ws + 3 * N_NODES;
        float* rep_acc = rep_deg + (size_t)NR * REP * RN;
        float* logit   = rep_acc + (size_t)NR * REP * RN * 2;

        k_deg_tiled     <<<NR * REP, 1024, 0, stream>>>(col, ea, rep_deg);
        k_dis           <<<gN, TB, 0, stream>>>(rep_deg, dis, logit);
        k_gemv          <<<gG, TB, 0, stream>>>(x, W, h);
        k_prop_tiled    <<<NR * REP, 1024, 0, stream>>>(row, col, ea, dis, h, rep_acc);
        k_epilogue_tiled<<<gN, TB, 0, stream>>>(rep_acc, h, dis, b, fcw, logit);
        k_sigmoid       <<<1, 1, 0, stream>>>(logit, fcb, out);
    } else {
        float* deg   = ws;
        float* h     = ws + N_NODES;
        float* accum = ws + 3 * N_NODES;
        float* logit = ws + 5 * N_NODES;
        dim3 gE((E_EDGES + TB - 1) / TB);
        k_init    <<<gN, TB, 0, stream>>>(deg, accum, logit);
        k_deg     <<<gE, TB, 0, stream>>>(col, ea, deg);
        k_rsqrt   <<<gN, TB, 0, stream>>>(deg);
        k_gemv    <<<gG, TB, 0, stream>>>(x, W, h);
        k_prop    <<<gE, TB, 0, stream>>>(row, col, ea, deg, h, accum);
        k_epilogue<<<gN, TB, 0, stream>>>(accum, h, deg, b, fcw, logit);
        k_sigmoid <<<1, 1, 0, stream>>>(logit, fcb, out);
    }
}

// Round 4
// 427.290 us; speedup vs baseline: 1.8487x; 1.0930x over previous
//
#include <hip/hip_runtime.h>
#include <math.h>

#define N_NODES 100000
#define F_IN    512
#define E_EDGES 3200000

// --- tiled-scatter geometry ---
#define NR   16                 // node ranges
#define RN   6250               // nodes per range (NR*RN == N_NODES)
#define REP  32                 // edge-chunk replicas (2 blocks/CU at 1024 thr)
#define CHUNK (E_EDGES / REP)   // 100000, multiple of 4

// ====================== fast path (LDS-tiled scatter) ======================

// deg scatter: block (r,p) accumulates attr of cols in range r from chunk p.
// col scanned vectorized; w gathered scalar only on range match (1/16).
__global__ __launch_bounds__(1024) void k_deg_tiled(const int* __restrict__ col,
                                                    const float* __restrict__ w,
                                                    float* __restrict__ rep_deg) {
    __shared__ float sdeg[RN];
    int r = blockIdx.x / REP, p = blockIdx.x % REP;
    int r0 = r * RN;
    for (int j = threadIdx.x; j < RN; j += 1024) sdeg[j] = 0.0f;
    __syncthreads();
    const int*   colc = col + p * CHUNK;
    const float* wc   = w   + p * CHUNK;
    for (int e4 = threadIdx.x * 4; e4 < CHUNK; e4 += 4096) {
        int4 c4 = *(const int4*)(colc + e4);
#pragma unroll
        for (int q = 0; q < 4; ++q) {
            unsigned j = (unsigned)((&c4.x)[q] - r0);
            if (j < RN) atomicAdd(&sdeg[j], wc[e4 + q]);
        }
    }
    __syncthreads();
    float* out = rep_deg + (size_t)blockIdx.x * RN;
    for (int j = threadIdx.x; j < RN; j += 1024) out[j] = sdeg[j];
}

// reduce replicas, add self-loop weight 1, rsqrt -> dis; zero logit
__global__ void k_dis(const float* __restrict__ rep_deg,
                      float* __restrict__ dis, float* __restrict__ logit) {
    int i = blockIdx.x * blockDim.x + threadIdx.x;
    if (i < N_NODES) {
        int r = i / RN, j = i - r * RN;
        const float* base = rep_deg + (size_t)(r * REP) * RN + j;
        float d = 1.0f;
#pragma unroll
        for (int p = 0; p < REP; ++p) d += base[p * RN];
        dis[i] = rsqrtf(d);
    }
    if (i == 0) logit[0] = 0.0f;
}

// g = (x @ W) * dis[row]  (wave-per-row, float4 coalesced, memory-bound)
__global__ __launch_bounds__(256) void k_gemv(const float* __restrict__ x,
                                              const float* __restrict__ W,
                                              const float* __restrict__ dis,
                                              float* __restrict__ g) {
    int row  = (blockIdx.x * blockDim.x + threadIdx.x) >> 6;
    int lane = threadIdx.x & 63;
    if (row >= N_NODES) return;
    const float* xr = x + (size_t)row * F_IN;
    float a0 = 0.0f, a1 = 0.0f;
#pragma unroll
    for (int c = 0; c < 2; ++c) {
        int k = c * 256 + lane * 4;
        float4 xv  = *(const float4*)(xr + k);
        float4 w01 = *(const float4*)(W + 2 * k);
        float4 w23 = *(const float4*)(W + 2 * k + 4);
        a0 += xv.x * w01.x + xv.y * w01.z + xv.z * w23.x + xv.w * w23.z;
        a1 += xv.x * w01.y + xv.y * w01.w + xv.z * w23.y + xv.w * w23.w;
    }
#pragma unroll
    for (int off = 32; off > 0; off >>= 1) {
        a0 += __shfl_down(a0, off, 64);
        a1 += __shfl_down(a1, off, 64);
    }
    if (lane == 0) {
        float d = dis[row];
        g[2 * row] = a0 * d;
        g[2 * row + 1] = a1 * d;
    }
}

// message scatter: sacc[col] += w[e] * g[row], LDS-tiled (dis[col] deferred)
__global__ __launch_bounds__(1024) void k_prop_tiled(const int* __restrict__ row,
                                                     const int* __restrict__ col,
                                                     const float* __restrict__ w,
                                                     const float* __restrict__ g,
                                                     float* __restrict__ rep_acc) {
    __shared__ float sacc[RN * 2];
    int r = blockIdx.x / REP, p = blockIdx.x % REP;
    int r0 = r * RN;
    for (int j = threadIdx.x; j < RN * 2; j += 1024) sacc[j] = 0.0f;
    __syncthreads();
    const int*   colc = col + p * CHUNK;
    const int*   rowc = row + p * CHUNK;
    const float* wc   = w   + p * CHUNK;
    for (int e4 = threadIdx.x * 4; e4 < CHUNK; e4 += 4096) {
        int4 c4 = *(const int4*)(colc + e4);
#pragma unroll
        for (int q = 0; q < 4; ++q) {
            unsigned j = (unsigned)((&c4.x)[q] - r0);
            if (j < RN) {
                int e  = e4 + q;
                int rr = rowc[e];
                float we = wc[e];
                float2 gv = *(const float2*)(g + 2 * rr);
                atomicAdd(&sacc[2 * j],     gv.x * we);
                atomicAdd(&sacc[2 * j + 1], gv.y * we);
            }
        }
    }
    __syncthreads();
    float* out = rep_acc + (size_t)blockIdx.x * (RN * 2);
    for (int j = threadIdx.x; j < RN * 2; j += 1024) out[j] = sacc[j];
}

// out[i] = relu(dis[i]*(sum_i + g[i]) + b); logit += out . fc_w
__global__ __launch_bounds__(256) void k_epilogue_tiled(const float* __restrict__ rep_acc,
                                                        const float* __restrict__ g,
                                                        const float* __restrict__ dis,
                                                        const float* __restrict__ b,
                                                        const float* __restrict__ fc_w,
                                                        float* __restrict__ logit) {
    int i = blockIdx.x * blockDim.x + threadIdx.x;
    float partial = 0.0f;
    if (i < N_NODES) {
        int r = i / RN, j = i - r * RN;
        const float2* base = (const float2*)rep_acc + (size_t)(r * REP) * RN + j;
        float o0 = 0.0f, o1 = 0.0f;
#pragma unroll
        for (int p = 0; p < REP; ++p) { float2 v = base[p * RN]; o0 += v.x; o1 += v.y; }
        float d = dis[i];
        o0 = (o0 + g[2 * i])     * d + b[0];   // self-loop: + g[i]*dis[i]
        o1 = (o1 + g[2 * i + 1]) * d + b[1];
        o0 = fmaxf(o0, 0.0f); o1 = fmaxf(o1, 0.0f);
        partial = o0 * fc_w[2 * i] + o1 * fc_w[2 * i + 1];
    }
#pragma unroll
    for (int off = 32; off > 0; off >>= 1)
        partial += __shfl_down(partial, off, 64);
    __shared__ float sdata[4];
    int lane = threadIdx.x & 63, wid = threadIdx.x >> 6;
    if (lane == 0) sdata[wid] = partial;
    __syncthreads();
    if (threadIdx.x == 0)
        atomicAdd(logit, sdata[0] + sdata[1] + sdata[2] + sdata[3]);
}

__global__ void k_sigmoid(const float* __restrict__ logit,
                          const float* __restrict__ fc_b,
                          float* __restrict__ out) {
    float z = logit[0] + fc_b[0];
    out[0] = 1.0f / (1.0f + expf(-z));
}

// ====================== fallback path (device atomics) ======================

__global__ void k_init(float* __restrict__ deg, float* __restrict__ accum,
                       float* __restrict__ logit) {
    int i = blockIdx.x * blockDim.x + threadIdx.x;
    if (i < N_NODES) {
        deg[i] = 1.0f;
        accum[2 * i] = 0.0f;
        accum[2 * i + 1] = 0.0f;
    }
    if (i == 0) logit[0] = 0.0f;
}

__global__ void k_deg(const int* __restrict__ col, const float* __restrict__ w,
                      float* __restrict__ deg) {
    int e = blockIdx.x * blockDim.x + threadIdx.x;
    if (e < E_EDGES) atomicAdd(&deg[col[e]], w[e]);
}

__global__ void k_rsqrt(float* __restrict__ deg) {
    int i = blockIdx.x * blockDim.x + threadIdx.x;
    if (i < N_NODES) deg[i] = rsqrtf(deg[i]);
}

__global__ void k_gemv_h(const float* __restrict__ x, const float* __restrict__ W,
                         float* __restrict__ h) {
    int row  = (blockIdx.x * blockDim.x + threadIdx.x) >> 6;
    int lane = threadIdx.x & 63;
    if (row >= N_NODES) return;
    const float* xr = x + (size_t)row * F_IN;
    float a0 = 0.0f, a1 = 0.0f;
#pragma unroll
    for (int c = 0; c < 2; ++c) {
        int k = c * 256 + lane * 4;
        float4 xv  = *(const float4*)(xr + k);
        float4 w01 = *(const float4*)(W + 2 * k);
        float4 w23 = *(const float4*)(W + 2 * k + 4);
        a0 += xv.x * w01.x + xv.y * w01.z + xv.z * w23.x + xv.w * w23.z;
        a1 += xv.x * w01.y + xv.y * w01.w + xv.z * w23.y + xv.w * w23.w;
    }
#pragma unroll
    for (int off = 32; off > 0; off >>= 1) {
        a0 += __shfl_down(a0, off, 64);
        a1 += __shfl_down(a1, off, 64);
    }
    if (lane == 0) { h[2 * row] = a0; h[2 * row + 1] = a1; }
}

__global__ void k_prop(const int* __restrict__ row, const int* __restrict__ col,
                       const float* __restrict__ w, const float* __restrict__ dis,
                       const float* __restrict__ h, float* __restrict__ accum) {
    int e = blockIdx.x * blockDim.x + threadIdx.x;
    if (e < E_EDGES) {
        int r = row[e], c = col[e];
        float nm = dis[r] * w[e] * dis[c];
        atomicAdd(&accum[2 * c],     h[2 * r] * nm);
        atomicAdd(&accum[2 * c + 1], h[2 * r + 1] * nm);
    }
}

__global__ __launch_bounds__(256) void k_epilogue(const float* __restrict__ accum,
                                                  const float* __restrict__ h,
                                                  const float* __restrict__ dis,
                                                  const float* __restrict__ b,
                                                  const float* __restrict__ fc_w,
                                                  float* __restrict__ logit) {
    int i = blockIdx.x * blockDim.x + threadIdx.x;
    float partial = 0.0f;
    if (i < N_NODES) {
        float d2 = dis[i] * dis[i];
        float o0 = accum[2 * i]     + h[2 * i]     * d2 + b[0];
        float o1 = accum[2 * i + 1] + h[2 * i + 1] * d2 + b[1];
        o0 = fmaxf(o0, 0.0f); o1 = fmaxf(o1, 0.0f);
        partial = o0 * fc_w[2 * i] + o1 * fc_w[2 * i + 1];
    }
#pragma unroll
    for (int off = 32; off > 0; off >>= 1)
        partial += __shfl_down(partial, off, 64);
    __shared__ float sdata[4];
    int lane = threadIdx.x & 63, wid = threadIdx.x >> 6;
    if (lane == 0) sdata[wid] = partial;
    __syncthreads();
    if (threadIdx.x == 0)
        atomicAdd(logit, sdata[0] + sdata[1] + sdata[2] + sdata[3]);
}

// ====================== launch ======================

extern "C" void kernel_launch(void* const* d_in, const int* in_sizes, int n_in,
                              void* d_out, int out_size, void* d_ws, size_t ws_size,
                              hipStream_t stream) {
    const float* x   = (const float*)d_in[0];
    const int*   el  = (const int*)d_in[1];    // [2, E] int32 on device
    const float* ea  = (const float*)d_in[2];
    const float* W   = (const float*)d_in[3];
    const float* b   = (const float*)d_in[4];
    const float* fcw = (const float*)d_in[5];
    const float* fcb = (const float*)d_in[6];
    float*       out = (float*)d_out;

    const int* row = el;
    const int* col = el + E_EDGES;

    float* ws = (float*)d_ws;
    const int TB = 256;
    dim3 gN((N_NODES + TB - 1) / TB);
    dim3 gG((N_NODES * 64 + TB - 1) / TB);

    // fast-path ws layout (floats):
    // g[2N] | dis[N] | rep_deg[NR*REP*RN] | rep_acc[NR*REP*RN*2] | logit[1]
    const size_t need_fast = (size_t)(3 * N_NODES +
                                      (size_t)NR * REP * RN * 3 + 64) * 4;

    if (ws_size >= need_fast) {
        float* g       = ws;
        float* dis     = ws + 2 * N_NODES;
        float* rep_deg = ws + 3 * N_NODES;
        float* rep_acc = rep_deg + (size_t)NR * REP * RN;
        float* logit   = rep_acc + (size_t)NR * REP * RN * 2;

        k_deg_tiled     <<<NR * REP, 1024, 0, stream>>>(col, ea, rep_deg);
        k_dis           <<<gN, TB, 0, stream>>>(rep_deg, dis, logit);
        k_gemv          <<<gG, TB, 0, stream>>>(x, W, dis, g);
        k_prop_tiled    <<<NR * REP, 1024, 0, stream>>>(row, col, ea, g, rep_acc);
        k_epilogue_tiled<<<gN, TB, 0, stream>>>(rep_acc, g, dis, b, fcw, logit);
        k_sigmoid       <<<1, 1, 0, stream>>>(logit, fcb, out);
    } else {
        float* deg   = ws;
        float* h     = ws + N_NODES;
        float* accum = ws + 3 * N_NODES;
        float* logit = ws + 5 * N_NODES;
        dim3 gE((E_EDGES + TB - 1) / TB);
        k_init    <<<gN, TB, 0, stream>>>(deg, accum, logit);
        k_deg     <<<gE, TB, 0, stream>>>(col, ea, deg);
        k_rsqrt   <<<gN, TB, 0, stream>>>(deg);
        k_gemv_h  <<<gG, TB, 0, stream>>>(x, W, h);
        k_prop    <<<gE, TB, 0, stream>>>(row, col, ea, deg, h, accum);
        k_epilogue<<<gN, TB, 0, stream>>>(accum, h, deg, b, fcw, logit);
        k_sigmoid <<<1, 1, 0, stream>>>(logit, fcb, out);
    }
}

// Round 5
// 411.204 us; speedup vs baseline: 1.9210x; 1.0391x over previous
//
#include <hip/hip_runtime.h>
#include <math.h>

#define N_NODES 100000
#define F_IN    512
#define E_EDGES 3200000

#define NR     16               // node ranges
#define RN     6250             // nodes per range (NR*RN == N_NODES)
#define SB     512              // sort scan blocks
#define SCHUNK (E_EDGES / SB)   // 6250 edges per scan block
#define SLICES 32               // slice blocks per range for LDS scatter
#define JMASK  0x1FFF           // 13 bits for j in [0,RN)

// ============ sort pass 1: per-(range, block) histogram ============
__global__ __launch_bounds__(256) void k_hist(const int* __restrict__ col,
                                              int* __restrict__ cnt) {
    __shared__ int hcnt[NR];
    int t = threadIdx.x;
    if (t < NR) hcnt[t] = 0;
    __syncthreads();
    int base = blockIdx.x * SCHUNK;
    for (int i = t; i < SCHUNK; i += 256) {
        int r = col[base + i] / RN;
        atomicAdd(&hcnt[r], 1);
    }
    __syncthreads();
    if (t < NR) cnt[t * SB + blockIdx.x] = hcnt[t];   // range-major
}

// ============ sort pass 2: exclusive prefix over NR*SB counts ============
__global__ __launch_bounds__(1024) void k_prefix(const int* __restrict__ cnt,
                                                 int* __restrict__ off) {
    __shared__ int psum[1024];
    int t = threadIdx.x;
    int v[8]; int s = 0;
    int base = t * 8;
#pragma unroll
    for (int k = 0; k < 8; ++k) { v[k] = s; s += cnt[base + k]; }
    psum[t] = s;
    __syncthreads();
    for (int d = 1; d < 1024; d <<= 1) {
        int add = (t >= d) ? psum[t - d] : 0;
        __syncthreads();
        psum[t] += add;
        __syncthreads();
    }
    int excl = psum[t] - s;
#pragma unroll
    for (int k = 0; k < 8; ++k) off[base + k] = excl + v[k];
    if (t == 1023) off[NR * SB] = psum[1023];
}

// ============ sort pass 3: scatter packed records into range order ============
__global__ __launch_bounds__(256) void k_scatter(const int* __restrict__ row,
                                                 const int* __restrict__ col,
                                                 const float* __restrict__ w,
                                                 const int* __restrict__ off,
                                                 unsigned* __restrict__ sidx,
                                                 float* __restrict__ sw) {
    __shared__ int cur[NR];
    int t = threadIdx.x;
    if (t < NR) cur[t] = off[t * SB + blockIdx.x];
    __syncthreads();
    int base = blockIdx.x * SCHUNK;
    for (int i = t; i < SCHUNK; i += 256) {
        int c  = col[base + i];
        int rr = row[base + i];
        float wv = w[base + i];
        int r = c / RN;
        int j = c - r * RN;
        int slot = atomicAdd(&cur[r], 1);
        sidx[slot] = (unsigned)j | ((unsigned)rr << 13);
        sw[slot]   = wv;
    }
}

// ============ deg scatter over sorted records (LDS tile, replicas) ============
__global__ __launch_bounds__(1024) void k_deg_s(const unsigned* __restrict__ sidx,
                                                const float* __restrict__ sw,
                                                const int* __restrict__ off,
                                                float* __restrict__ rep_deg) {
    __shared__ float sdeg[RN];
    int r = blockIdx.x / SLICES, s = blockIdx.x % SLICES;
    int lo_r = off[r * SB], hi_r = off[(r + 1) * SB];
    int len = hi_r - lo_r;
    int lo = lo_r + len * s / SLICES;
    int hi = lo_r + len * (s + 1) / SLICES;
    for (int j = threadIdx.x; j < RN; j += 1024) sdeg[j] = 0.0f;
    __syncthreads();
    for (int i = lo + threadIdx.x; i < hi; i += 1024) {
        unsigned u = sidx[i];
        atomicAdd(&sdeg[u & JMASK], sw[i]);
    }
    __syncthreads();
    float* out = rep_deg + (size_t)blockIdx.x * RN;
    for (int j = threadIdx.x; j < RN; j += 1024) out[j] = sdeg[j];
}

// ============ reduce replicas -> dis = rsqrt(1+deg); zero logit ============
__global__ void k_dis(const float* __restrict__ rep_deg,
                      float* __restrict__ dis, float* __restrict__ logit) {
    int i = blockIdx.x * blockDim.x + threadIdx.x;
    if (i < N_NODES) {
        int r = i / RN, j = i - r * RN;
        const float* base = rep_deg + (size_t)(r * SLICES) * RN + j;
        float d = 1.0f;
#pragma unroll
        for (int p = 0; p < SLICES; ++p) d += base[p * RN];
        dis[i] = rsqrtf(d);
    }
    if (i == 0) logit[0] = 0.0f;
}

// ============ g = (x @ W) * dis  (wave-per-row, memory-bound) ============
__global__ __launch_bounds__(256) void k_gemv(const float* __restrict__ x,
                                              const float* __restrict__ W,
                                              const float* __restrict__ dis,
                                              float* __restrict__ g) {
    int row  = (blockIdx.x * blockDim.x + threadIdx.x) >> 6;
    int lane = threadIdx.x & 63;
    if (row >= N_NODES) return;
    const float* xr = x + (size_t)row * F_IN;
    float a0 = 0.0f, a1 = 0.0f;
#pragma unroll
    for (int c = 0; c < 2; ++c) {
        int k = c * 256 + lane * 4;
        float4 xv  = *(const float4*)(xr + k);
        float4 w01 = *(const float4*)(W + 2 * k);
        float4 w23 = *(const float4*)(W + 2 * k + 4);
        a0 += xv.x * w01.x + xv.y * w01.z + xv.z * w23.x + xv.w * w23.z;
        a1 += xv.x * w01.y + xv.y * w01.w + xv.z * w23.y + xv.w * w23.w;
    }
#pragma unroll
    for (int off = 32; off > 0; off >>= 1) {
        a0 += __shfl_down(a0, off, 64);
        a1 += __shfl_down(a1, off, 64);
    }
    if (lane == 0) {
        float d = dis[row];
        g[2 * row]     = a0 * d;
        g[2 * row + 1] = a1 * d;
    }
}

// ============ message scatter over sorted records ============
__global__ __launch_bounds__(1024) void k_prop_s(const unsigned* __restrict__ sidx,
                                                 const float* __restrict__ sw,
                                                 const int* __restrict__ off,
                                                 const float* __restrict__ g,
                                                 float* __restrict__ rep_acc) {
    __shared__ float sacc[RN * 2];
    int r = blockIdx.x / SLICES, s = blockIdx.x % SLICES;
    int lo_r = off[r * SB], hi_r = off[(r + 1) * SB];
    int len = hi_r - lo_r;
    int lo = lo_r + len * s / SLICES;
    int hi = lo_r + len * (s + 1) / SLICES;
    for (int j = threadIdx.x; j < RN * 2; j += 1024) sacc[j] = 0.0f;
    __syncthreads();
    for (int i = lo + threadIdx.x; i < hi; i += 1024) {
        unsigned u = sidx[i];
        int j  = u & JMASK;
        int rr = u >> 13;
        float we = sw[i];
        float2 gv = *(const float2*)(g + 2 * rr);
        atomicAdd(&sacc[2 * j],     gv.x * we);
        atomicAdd(&sacc[2 * j + 1], gv.y * we);
    }
    __syncthreads();
    float* out = rep_acc + (size_t)blockIdx.x * (RN * 2);
    for (int j = threadIdx.x; j < RN * 2; j += 1024) out[j] = sacc[j];
}

// ============ epilogue: replica-reduce + self-loop + relu + fc dot ============
__global__ __launch_bounds__(256) void k_epilogue(const float* __restrict__ rep_acc,
                                                  const float* __restrict__ g,
                                                  const float* __restrict__ dis,
                                                  const float* __restrict__ b,
                                                  const float* __restrict__ fc_w,
                                                  float* __restrict__ logit) {
    int i = blockIdx.x * blockDim.x + threadIdx.x;
    float partial = 0.0f;
    if (i < N_NODES) {
        int r = i / RN, j = i - r * RN;
        const float2* base = (const float2*)rep_acc + (size_t)(r * SLICES) * RN + j;
        float o0 = 0.0f, o1 = 0.0f;
#pragma unroll
        for (int p = 0; p < SLICES; ++p) { float2 v = base[p * RN]; o0 += v.x; o1 += v.y; }
        float d = dis[i];
        o0 = (o0 + g[2 * i])     * d + b[0];   // self-loop term: g[i]*dis[i]
        o1 = (o1 + g[2 * i + 1]) * d + b[1];
        o0 = fmaxf(o0, 0.0f); o1 = fmaxf(o1, 0.0f);
        partial = o0 * fc_w[2 * i] + o1 * fc_w[2 * i + 1];
    }
#pragma unroll
    for (int off = 32; off > 0; off >>= 1)
        partial += __shfl_down(partial, off, 64);
    __shared__ float sdata[4];
    int lane = threadIdx.x & 63, wid = threadIdx.x >> 6;
    if (lane == 0) sdata[wid] = partial;
    __syncthreads();
    if (threadIdx.x == 0)
        atomicAdd(logit, sdata[0] + sdata[1] + sdata[2] + sdata[3]);
}

__global__ void k_sigmoid(const float* __restrict__ logit,
                          const float* __restrict__ fc_b,
                          float* __restrict__ out) {
    float z = logit[0] + fc_b[0];
    out[0] = 1.0f / (1.0f + expf(-z));
}

// ====================== fallback path (device atomics) ======================

__global__ void k_init_f(float* __restrict__ deg, float* __restrict__ accum,
                         float* __restrict__ logit) {
    int i = blockIdx.x * blockDim.x + threadIdx.x;
    if (i < N_NODES) {
        deg[i] = 1.0f;
        accum[2 * i] = 0.0f;
        accum[2 * i + 1] = 0.0f;
    }
    if (i == 0) logit[0] = 0.0f;
}

__global__ void k_deg_f(const int* __restrict__ col, const float* __restrict__ w,
                        float* __restrict__ deg) {
    int e = blockIdx.x * blockDim.x + threadIdx.x;
    if (e < E_EDGES) atomicAdd(&deg[col[e]], w[e]);
}

__global__ void k_rsqrt_f(float* __restrict__ deg) {
    int i = blockIdx.x * blockDim.x + threadIdx.x;
    if (i < N_NODES) deg[i] = rsqrtf(deg[i]);
}

__global__ void k_prop_f(const int* __restrict__ row, const int* __restrict__ col,
                         const float* __restrict__ w, const float* __restrict__ dis,
                         const float* __restrict__ g, float* __restrict__ accum) {
    int e = blockIdx.x * blockDim.x + threadIdx.x;
    if (e < E_EDGES) {
        int r = row[e], c = col[e];
        float nm = w[e];
        atomicAdd(&accum[2 * c],     g[2 * r] * nm);
        atomicAdd(&accum[2 * c + 1], g[2 * r + 1] * nm);
    }
}

__global__ __launch_bounds__(256) void k_epilogue_f(const float* __restrict__ accum,
                                                    const float* __restrict__ g,
                                                    const float* __restrict__ dis,
                                                    const float* __restrict__ b,
                                                    const float* __restrict__ fc_w,
                                                    float* __restrict__ logit) {
    int i = blockIdx.x * blockDim.x + threadIdx.x;
    float partial = 0.0f;
    if (i < N_NODES) {
        float d = dis[i];
        float o0 = (accum[2 * i]     + g[2 * i])     * d + b[0];
        float o1 = (accum[2 * i + 1] + g[2 * i + 1]) * d + b[1];
        o0 = fmaxf(o0, 0.0f); o1 = fmaxf(o1, 0.0f);
        partial = o0 * fc_w[2 * i] + o1 * fc_w[2 * i + 1];
    }
#pragma unroll
    for (int off = 32; off > 0; off >>= 1)
        partial += __shfl_down(partial, off, 64);
    __shared__ float sdata[4];
    int lane = threadIdx.x & 63, wid = threadIdx.x >> 6;
    if (lane == 0) sdata[wid] = partial;
    __syncthreads();
    if (threadIdx.x == 0)
        atomicAdd(logit, sdata[0] + sdata[1] + sdata[2] + sdata[3]);
}

// ====================== launch ======================

extern "C" void kernel_launch(void* const* d_in, const int* in_sizes, int n_in,
                              void* d_out, int out_size, void* d_ws, size_t ws_size,
                              hipStream_t stream) {
    const float* x   = (const float*)d_in[0];
    const int*   el  = (const int*)d_in[1];    // [2, E] int32 on device
    const float* ea  = (const float*)d_in[2];
    const float* W   = (const float*)d_in[3];
    const float* b   = (const float*)d_in[4];
    const float* fcw = (const float*)d_in[5];
    const float* fcb = (const float*)d_in[6];
    float*       out = (float*)d_out;

    const int* row = el;
    const int* col = el + E_EDGES;

    float* ws = (float*)d_ws;
    const int TB = 256;
    dim3 gN((N_NODES + TB - 1) / TB);
    dim3 gG((N_NODES * 64 + TB - 1) / TB);

    // fast-path ws layout (4B units):
    // g[2N] | dis[N] | logit[1] | pad | cnt[NR*SB] | off[NR*SB+1] | pad |
    // sidx[E] | sw[E] | rep_deg[NR*SLICES*RN] | rep_acc[NR*SLICES*RN*2]
    size_t o_g    = 0;
    size_t o_dis  = o_g + 2 * N_NODES;
    size_t o_log  = o_dis + N_NODES;
    size_t o_cnt  = (o_log + 64) & ~63ull;
    size_t o_off  = o_cnt + NR * SB;
    size_t o_sidx = (o_off + NR * SB + 1 + 63) & ~63ull;
    size_t o_sw   = o_sidx + E_EDGES;
    size_t o_rd   = o_sw + E_EDGES;
    size_t o_ra   = o_rd + (size_t)NR * SLICES * RN;
    size_t need_fast = (o_ra + (size_t)NR * SLICES * RN * 2) * 4;

    if (ws_size >= need_fast) {
        float*    g       = ws + o_g;
        float*    dis     = ws + o_dis;
        float*    logit   = ws + o_log;
        int*      cnt     = (int*)(ws + o_cnt);
        int*      off     = (int*)(ws + o_off);
        unsigned* sidx    = (unsigned*)(ws + o_sidx);
        float*    sw      = ws + o_sw;
        float*    rep_deg = ws + o_rd;
        float*    rep_acc = ws + o_ra;

        k_hist    <<<SB, 256, 0, stream>>>(col, cnt);
        k_prefix  <<<1, 1024, 0, stream>>>(cnt, off);
        k_scatter <<<SB, 256, 0, stream>>>(row, col, ea, off, sidx, sw);
        k_deg_s   <<<NR * SLICES, 1024, 0, stream>>>(sidx, sw, off, rep_deg);
        k_dis     <<<gN, TB, 0, stream>>>(rep_deg, dis, logit);
        k_gemv    <<<gG, TB, 0, stream>>>(x, W, dis, g);
        k_prop_s  <<<NR * SLICES, 1024, 0, stream>>>(sidx, sw, off, g, rep_acc);
        k_epilogue<<<gN, TB, 0, stream>>>(rep_acc, g, dis, b, fcw, logit);
        k_sigmoid <<<1, 1, 0, stream>>>(logit, fcb, out);
    } else {
        float* deg   = ws;
        float* g     = ws + N_NODES;
        float* accum = ws + 3 * N_NODES;
        float* logit = ws + 5 * N_NODES;
        dim3 gE((E_EDGES + TB - 1) / TB);
        k_init_f    <<<gN, TB, 0, stream>>>(deg, accum, logit);
        k_deg_f     <<<gE, TB, 0, stream>>>(col, ea, deg);
        k_rsqrt_f   <<<gN, TB, 0, stream>>>(deg);
        k_gemv      <<<gG, TB, 0, stream>>>(x, W, deg, g);
        k_prop_f    <<<gE, TB, 0, stream>>>(row, col, ea, deg, g, accum);
        k_epilogue_f<<<gN, TB, 0, stream>>>(accum, g, deg, b, fcw, logit);
        k_sigmoid   <<<1, 1, 0, stream>>>(logit, fcb, out);
    }
}